// Round 7
// baseline (287.740 us; speedup 1.0000x reference)
//
#include <hip/hip_runtime.h>
#include <cstddef>

typedef __bf16 bf16;
typedef __bf16 bf16x4 __attribute__((ext_vector_type(4)));
typedef __bf16 bf16x8 __attribute__((ext_vector_type(8)));
typedef float  f32x4  __attribute__((ext_vector_type(4)));

#define MFMA16(a, b, c) __builtin_amdgcn_mfma_f32_16x16x32_bf16((a), (b), (c), 0, 0, 0)

// ---------------- constants ----------------
#define BB 8
#define CC 2048
#define DD 128
#define JJN 128

// ws layout (bytes)
#define WS_PK    ((size_t)0)          // bf16 [8][64jc][8nb][4q][16m][8e]
#define WS_OPS16 ((size_t)8388608)    // bf16 [8][2048][128]
#define WS_SQF   ((size_t)12582912)   // f32  [8][2048]
#define WS_SKF   ((size_t)12648448)   // f32  [8][2048]
#define WS_G1T   ((size_t)12713984)   // bf16 [128][128] (transposed: [e][d])
#define WS_G2T   ((size_t)12746752)
#define WS_G3T   ((size_t)12779520)
#define WS_WCT   ((size_t)12812288)
#define WS_GBT   ((size_t)12845056)
#define WS_GET   ((size_t)12877824)
#define WS_UQK   ((size_t)12910592)   // bf16 [2][128]
#define WS_BBM   ((size_t)12911104)   // f32 [128]
#define WS_BBB   ((size_t)12911616)   // f32 [128]
#define WS_BBE   ((size_t)12912128)   // f32 [128]
#define WS_SC    ((size_t)12912640)   // f32 [2]
#define WS_WCN   ((size_t)12913152)   // bf16 [128][128] non-transposed [d][e]
#define WS_GBN   ((size_t)12945920)
#define WS_GEN   ((size_t)12978688)
#define WS_MB    ((size_t)13011456)   // u8  [8][2048][256] packed mask bits (4 MiB)
#define WS_MEANV ((size_t)17205760)   // f32 [16][128] begin/end gather means
#define WS_PARTO ((size_t)33554432)   // f32 [1024][32][128] partial O (16 MB)
#define WS_PARTL ((size_t)50331648)   // f32 [1024][32] partial lsum

// =====================================================================
// Kernel PREPCAST (unchanged from round 6)
// =====================================================================
__global__ __launch_bounds__(256) void k_prepcast(
    const float* __restrict__ ops, bf16* __restrict__ ops16,
    const int* __restrict__ begins, const int* __restrict__ ends,
    const float* __restrict__ Wmix3, const float* __restrict__ Wmix2,
    const float* __restrict__ Wout,  const float* __restrict__ Wbegin,
    const float* __restrict__ Wend,  const float* __restrict__ Wqkv,
    const float* __restrict__ bqkv,  const float* __restrict__ wscore,
    const float* __restrict__ bscore,const float* __restrict__ bmix3,
    const float* __restrict__ bout,  const float* __restrict__ bmix2,
    const float* __restrict__ bbegin,const float* __restrict__ bend,
    bf16* __restrict__ G1T, bf16* __restrict__ G2T, bf16* __restrict__ G3T,
    bf16* __restrict__ WCT, bf16* __restrict__ GBT, bf16* __restrict__ GET,
    bf16* __restrict__ WCN, bf16* __restrict__ GBN, bf16* __restrict__ GEN,
    bf16* __restrict__ uqk, float* __restrict__ BBM, float* __restrict__ BBB,
    float* __restrict__ BBE, float* __restrict__ sc, float* __restrict__ MEANV)
{
    __shared__ bf16  LshT[128 * 132];
    __shared__ float Rsh[128 * 8];
    int wg = blockIdx.x;
    int t  = threadIdx.x;

    if (wg == 0) {
        for (int half = 0; half < 2; ++half) {
            #pragma unroll
            for (int pass = 0; pass < 16; ++pass) {       // stage [e][d]
                int idx = pass * 256 + t;
                int d   = idx >> 5;
                int e0  = (idx & 31) * 4;
                f32x4 v = *(const f32x4*)(Wqkv + d*384 + half*128 + e0);
                #pragma unroll
                for (int jj = 0; jj < 4; ++jj)
                    LshT[(e0 + jj)*132 + d] = (bf16)v[jj];
            }
            if (t < 32) {
                f32x4 wv = *(const f32x4*)(wscore + half*128 + t*4);
                #pragma unroll
                for (int jj = 0; jj < 4; ++jj) Rsh[t*4 + jj] = wv[jj];
            }
            __syncthreads();
            if (t < 128) {
                float s = 0.f;
                for (int e = 0; e < 128; ++e)
                    s += (float)LshT[e*132 + t] * Rsh[e];
                uqk[half*128 + t] = (bf16)s;
            }
            __syncthreads();
        }
        float bm = 0.f, bb_ = 0.f, be_ = 0.f, bon = 0.f;
        for (int half = 0; half < 2; ++half) {
            #pragma unroll
            for (int pass = 0; pass < 16; ++pass) {       // stage [f][e]
                int idx = pass * 256 + t;
                int f   = idx >> 5;
                int e0  = (idx & 31) * 4;
                f32x4 v = *(const f32x4*)(Wmix2 + (size_t)(half*128 + f)*128 + e0);
                #pragma unroll
                for (int jj = 0; jj < 4; ++jj)
                    LshT[f*132 + e0 + jj] = (bf16)v[jj];
            }
            if (t < 32) {
                if (half == 0) {
                    f32x4 v0 = *(const f32x4*)(bmix3  + t*4);
                    f32x4 v1 = *(const f32x4*)(bbegin + t*4);
                    f32x4 v2 = *(const f32x4*)(bend   + t*4);
                    #pragma unroll
                    for (int jj = 0; jj < 4; ++jj) {
                        Rsh[t*4 + jj]       = v0[jj];
                        Rsh[128 + t*4 + jj] = v1[jj];
                        Rsh[256 + t*4 + jj] = v2[jj];
                    }
                } else {
                    f32x4 v3 = *(const f32x4*)(bout + t*4);
                    #pragma unroll
                    for (int jj = 0; jj < 4; ++jj) Rsh[t*4 + jj] = v3[jj];
                }
            }
            __syncthreads();
            if (t < 128) {
                if (half == 0) {
                    for (int f = 0; f < 128; ++f) {
                        float wv = (float)LshT[f*132 + t];
                        bm  += Rsh[f]       * wv;
                        bb_ += Rsh[128 + f] * wv;
                        be_ += Rsh[256 + f] * wv;
                    }
                } else {
                    for (int f = 0; f < 128; ++f)
                        bon += Rsh[f] * (float)LshT[f*132 + t];
                }
            }
            __syncthreads();
        }
        if (t < 128) {
            float bm2 = bmix2[t];
            BBM[t] = bm  + bon + bm2;
            BBB[t] = bb_ + bon + bm2;
            BBE[t] = be_ + bon + bm2;
        }
        if (t >= 128) {
            int e2 = t - 128;
            Rsh[512 + e2] = bqkv[e2]       * wscore[e2];
            Rsh[640 + e2] = bqkv[128 + e2] * wscore[128 + e2];
        }
        __syncthreads();
        if (t == 0) {
            float cq = 0.f, ck = 0.f;
            for (int e2 = 0; e2 < 128; ++e2) {
                cq += Rsh[512 + e2];
                ck += Rsh[640 + e2];
            }
            sc[0] = cq + bscore[0];
            sc[1] = ck;
        }
        return;
    }
    if (wg <= 16) {
        int task = wg - 1;
        int b2 = task >> 1, which = task & 1;
        const int* idxp = which ? (ends + b2 * JJN) : (begins + b2 * JJN);
        int* ish = (int*)Rsh;
        if (t < JJN) ish[t] = idxp[t];
        __syncthreads();
        int d = t & 127, half = t >> 7;
        const float* opsb = ops + (size_t)b2 * CC * DD;
        float s = 0.f;
        #pragma unroll 8
        for (int j = 0; j < 64; ++j) {
            int r = ish[half * 64 + j];
            s += opsb[(size_t)r * DD + d];
        }
        float* fsh = Rsh + 256;
        fsh[half * 128 + d] = s;
        __syncthreads();
        if (t < 128)
            MEANV[task * 128 + t] = (fsh[t] + fsh[128 + t]) * (1.0f / (float)JJN);
        return;
    }
    if (wg <= 112) {
        int id  = wg - 17;
        int mat = id >> 4, sub = id & 15;
        const float* L; const float* R; bf16* O; bf16* O2;
        switch (mat) {
            case 0: L = Wmix3;           R = Wmix2;           O = G1T; O2 = nullptr; break;
            case 1: L = Wmix3 + 128*128; R = Wmix2;           O = G2T; O2 = nullptr; break;
            case 2: L = Wmix3 + 256*128; R = Wmix2;           O = G3T; O2 = nullptr; break;
            case 3: L = Wout;            R = Wmix2 + 128*128; O = WCT; O2 = WCN; break;
            case 4: L = Wbegin;          R = Wmix2;           O = GBT; O2 = GBN; break;
            default:L = Wend;            R = Wmix2;           O = GET; O2 = GEN; break;
        }
        int e0 = sub * 8;
        #pragma unroll
        for (int pass = 0; pass < 16; ++pass) {
            int idx = pass * 256 + t;
            int d   = idx >> 5;
            int f0  = (idx & 31) * 4;
            f32x4 v = *(const f32x4*)(L + d * 128 + f0);
            #pragma unroll
            for (int jj = 0; jj < 4; ++jj)
                LshT[(f0 + jj) * 132 + d] = (bf16)v[jj];
        }
        #pragma unroll
        for (int pass = 0; pass < 4; ++pass) {
            int idx = pass * 256 + t;
            int f   = idx >> 3;
            int ee  = idx & 7;
            Rsh[f * 8 + ee] = R[f * 128 + e0 + ee];
        }
        __syncthreads();
        int ee = t >> 5;
        int e  = e0 + ee;
        int d0 = (t & 31) * 4;
        float s[4] = {0.f, 0.f, 0.f, 0.f};
        for (int f = 0; f < 128; ++f) {
            bf16x4 lv = *(const bf16x4*)&LshT[f * 132 + d0];
            float rv = Rsh[f * 8 + ee];
            #pragma unroll
            for (int dd = 0; dd < 4; ++dd)
                s[dd] += (float)lv[dd] * rv;
        }
        #pragma unroll
        for (int dd = 0; dd < 4; ++dd) {
            O[e * 128 + d0 + dd] = (bf16)s[dd];
            if (O2) O2[(d0 + dd) * 128 + e] = (bf16)s[dd];
        }
        return;
    }
    // ---- cast ----
    size_t i = (size_t)(wg - 113) * 256 + t;
    f32x4 a = *(const f32x4*)(ops + i * 8);
    f32x4 b = *(const f32x4*)(ops + i * 8 + 4);
    bf16x8 o;
    #pragma unroll
    for (int e = 0; e < 4; ++e) { o[e] = (bf16)a[e]; o[4 + e] = (bf16)b[e]; }
    *(bf16x8*)(ops16 + i * 8) = o;
}

// =====================================================================
// Kernel V (unchanged from round 6): blocks 0..255 = V GEMM into PK;
// blocks 256..2303 = mask bit-pack.
// =====================================================================
__global__ __launch_bounds__(256) void k_v(
    const bf16* __restrict__ ops16, const float* __restrict__ Wqkv,
    const float* __restrict__ bqkv, const bf16* __restrict__ uqk,
    const float* __restrict__ sc,   const float* __restrict__ mask,
    bf16* __restrict__ PK, float* __restrict__ sqf, float* __restrict__ skf,
    unsigned char* __restrict__ MBITS)
{
    __shared__ bf16 A[144 * 136];
    int t = threadIdx.x;
    if (blockIdx.x >= 256) {
        int p = blockIdx.x - 256;
        size_t base = (size_t)p * 16384;
        const float* mp = mask + base;
        unsigned char* ob = MBITS + (base >> 3);
        #pragma unroll
        for (int k = 0; k < 8; ++k) {
            size_t fo = (size_t)k * 2048 + (size_t)t * 8;
            f32x4 a = __builtin_nontemporal_load((const f32x4*)(mp + fo));
            f32x4 c = __builtin_nontemporal_load((const f32x4*)(mp + fo + 4));
            unsigned byte = 0;
            #pragma unroll
            for (int e = 0; e < 4; ++e) {
                byte |= (a[e] != 0.f ? 1u : 0u) << e;
                byte |= (c[e] != 0.f ? 1u : 0u) << (4 + e);
            }
            ob[k * 256 + t] = (unsigned char)byte;
        }
        return;
    }
    int b  = blockIdx.x & 7;
    int jt = (blockIdx.x >> 3) * 64;
    #pragma unroll
    for (int pass = 0; pass < 16; ++pass) {
        int idx = pass * 256 + t;
        int d   = idx >> 5;
        int n0  = (idx & 31) * 4;
        f32x4 v = *(const f32x4*)(Wqkv + d*384 + 256 + n0);
        #pragma unroll
        for (int jj = 0; jj < 4; ++jj)
            A[(n0 + jj)*136 + d] = (bf16)v[jj];
    }
    {
        int row = t >> 7, col = t & 127;
        A[(128 + row)*136 + col] = uqk[row*128 + col];
    }
    for (int idx = t; idx < 14*136; idx += 256)
        A[130*136 + idx] = (bf16)0.f;
    __syncthreads();

    int lane = t & 63, w = t >> 6;
    int m = lane & 15, q = lane >> 4;
    f32x4 acc[9];
    #pragma unroll
    for (int rb = 0; rb < 9; ++rb) acc[rb] = {0.f, 0.f, 0.f, 0.f};

    const bf16* opsb = ops16 + (size_t)b * CC * DD;
    int j = jt + w*16 + m;
    #pragma unroll
    for (int kc = 0; kc < 4; ++kc) {
        bf16x8 bfr = *(const bf16x8*)(opsb + (size_t)j*DD + kc*32 + q*8);
        #pragma unroll
        for (int rb = 0; rb < 9; ++rb) {
            bf16x8 afr = *(const bf16x8*)&A[(rb*16 + m)*136 + kc*32 + q*8];
            acc[rb] = MFMA16(afr, bfr, acc[rb]);
        }
    }
    float cqb = sc[0], ckv = sc[1];
    if (q == 0) {
        sqf[b*CC + j] = acc[8][0] + cqb;
        skf[b*CC + j] = acc[8][1] + ckv;
    }
    __syncthreads();
    bf16* pack = A;
    {
        int jcl = w >> 1;
        int qv  = (w & 1) * 2 + (m >> 3);
        int ev  = m & 7;
        #pragma unroll
        for (int rb = 0; rb < 8; ++rb) {
            #pragma unroll
            for (int r = 0; r < 4; ++r) {
                float v = acc[rb][r] + bqkv[256 + rb*16 + q*4 + r];
                pack[jcl*4096 + rb*512 + qv*128 + (q*4+r)*8 + ev] = (bf16)v;
            }
        }
    }
    __syncthreads();
    bf16* pkb = PK + (size_t)b * DD * CC + (size_t)jt * 128;
    #pragma unroll
    for (int pass = 0; pass < 4; ++pass) {
        int lidx = pass * 256 + t;
        *(uint4*)(pkb + (size_t)lidx * 8) = *(const uint4*)&pack[lidx * 8];
    }
}

// =====================================================================
// Kernel ATT (phase A only, j-split): 1024 blocks = (jh, it, b).
// Each wave: 16-row tile (tl) x 256-j window (jg) = 8 chunks.
// Writes f32 partial O + partial lsum to workspace.
// =====================================================================
__device__ __forceinline__ void load_vb(const bf16* __restrict__ pkb, int jc,
                                        int q, int m, bf16x8 vb[8])
{
    #pragma unroll
    for (int nb = 0; nb < 8; ++nb)
        vb[nb] = *(const bf16x8*)(pkb + ((size_t)(((jc*8 + nb)*4 + q)*16 + m)) * 8);
}

__global__ __launch_bounds__(512, 2) void k_att(
    const unsigned char* __restrict__ MBITS, const bf16* __restrict__ PK,
    const float* __restrict__ sqf, const float* __restrict__ skf,
    float* __restrict__ PARTO, float* __restrict__ PARTL)
{
    __shared__ __align__(16) char smem[34048];
    int t    = threadIdx.x;
    int lane = t & 63, w = t >> 6;             // w = 0..7
    int b    = blockIdx.x & 7;
    int it   = (blockIdx.x >> 3) & 63;
    int jh   = blockIdx.x >> 9;                // 0/1: which 1024-j half
    int i0   = it << 5;
    int m = lane & 15, q = lane >> 4;
    int tl = w & 1;                            // 16-row tile of this wave
    int jg = w >> 1;                           // 256-j group (0..3) in half

    unsigned char* Lb  = (unsigned char*)smem;          // [32][136] bytes
    float*         skw = (float*)(smem + 4352);         // [1024] f32

    // ---- stage: this half's mask bits (4 KB) + sk half-row (4 KB) ----
    {
        int row = t >> 4, seg = t & 15;
        *(uint2*)(Lb + row * 136 + seg * 8) = *(const uint2*)(MBITS
            + ((size_t)(b * CC + i0 + row)) * 256 + jh * 128 + seg * 8);
    }
    if (t < 256)
        *(f32x4*)(skw + t * 4) = *(const f32x4*)(skf + b * CC + jh * 1024 + t * 4);

    float sq = sqf[b * CC + i0 + tl * 16 + m];
    const bf16* pkb = PK + (size_t)b * DD * CC;
    const float* skg = skw + jg * 256;

    f32x4 acc[8];
    #pragma unroll
    for (int nb = 0; nb < 8; ++nb) acc[nb] = {0.f, 0.f, 0.f, 0.f};
    float lsum = 0.f;
    __syncthreads();

    // ---- phase A: 8 chunks of 32 j per wave ----
    #pragma unroll
    for (int c = 0; c < 8; ++c) {
        int jcl = jg * 8 + c;                  // local chunk in half (0..31)
        int jc  = jh * 32 + jcl;               // global chunk
        bf16x8 vb[8];
        load_vb(pkb, jc, q, m, vb);
        unsigned mb = Lb[(tl * 16 + m) * 136 + jcl * 4 + q];
        int jo = c * 32 + q * 8;
        f32x4 s0 = *(const f32x4*)(skg + jo);
        f32x4 s1 = *(const f32x4*)(skg + jo + 4);
        float sks[8] = {s0[0], s0[1], s0[2], s0[3], s1[0], s1[1], s1[2], s1[3]};
        bf16x8 a;
        #pragma unroll
        for (int e = 0; e < 8; ++e) {
            float tv = sq + sks[e];
            float lr = fmaxf(tv, 0.01f * tv);
            float p  = __expf(lr * (float)((mb >> e) & 1u));
            lsum += p;
            a[e] = (bf16)p;
        }
        #pragma unroll
        for (int nb = 0; nb < 8; ++nb)
            acc[nb] = MFMA16(a, vb[nb], acc[nb]);
    }

    lsum += __shfl_xor(lsum, 16, 64);
    lsum += __shfl_xor(lsum, 32, 64);

    __syncthreads();                           // Lb/skw dead; Osh overlays

    // ---- 2-plane fold of the 4 j-group partials -> global partials ----
    float* Osh = (float*)smem;                 // [2][32][132] f32 = 33792 B
    float* Lsh = (float*)(smem + 33792);       // [64] f32
    {
        int plane = jg & 1;
        int orow  = plane * 32 + tl * 16;
        if (jg < 2) {
            if (q == 0) Lsh[plane * 32 + tl * 16 + m] = lsum;
            #pragma unroll
            for (int nb = 0; nb < 8; ++nb)
                #pragma unroll
                for (int r = 0; r < 4; ++r)
                    Osh[(orow + q * 4 + r) * 132 + nb * 16 + m] = acc[nb][r];
        }
        __syncthreads();
        if (jg >= 2) {
            if (q == 0) Lsh[plane * 32 + tl * 16 + m] += lsum;
            #pragma unroll
            for (int nb = 0; nb < 8; ++nb)
                #pragma unroll
                for (int r = 0; r < 4; ++r)
                    Osh[(orow + q * 4 + r) * 132 + nb * 16 + m] += acc[nb][r];
        }
        __syncthreads();
        // combine plane0+plane1, write f32 partial (coalesced)
        int r   = t >> 4;                       // 0..31
        int c0e = (t & 15) * 8;
        size_t idx = (size_t)((b * 64 + it) * 2 + jh);
        float* po = PARTO + idx * 4096;
        f32x4 o0, o1;
        #pragma unroll
        for (int e = 0; e < 4; ++e) {
            o0[e] = Osh[r * 132 + c0e + e]     + Osh[(32 + r) * 132 + c0e + e];
            o1[e] = Osh[r * 132 + c0e + 4 + e] + Osh[(32 + r) * 132 + c0e + 4 + e];
        }
        *(f32x4*)(po + r * 128 + c0e)     = o0;
        *(f32x4*)(po + r * 128 + c0e + 4) = o1;
        if ((t & 15) == 0)
            PARTL[idx * 32 + r] = Lsh[r] + Lsh[32 + r];
    }
}

// =====================================================================
// Kernel EPI: 512 blocks (b, it), 256 threads. Sums the 2 j-half
// partials, normalizes -> Obuf, then the proven 256-thread 4-term
// output GEMM + edge rows (from round 4).
// =====================================================================
__global__ __launch_bounds__(256) void k_epi(
    const float* __restrict__ PARTO, const float* __restrict__ PARTL,
    const bf16* __restrict__ ops16, const int* __restrict__ relations,
    const bf16* __restrict__ G1T, const bf16* __restrict__ G2T,
    const bf16* __restrict__ G3T, const bf16* __restrict__ WCT,
    const bf16* __restrict__ GBN, const bf16* __restrict__ GEN,
    const bf16* __restrict__ WCN,
    const float* __restrict__ BBM, const float* __restrict__ BBB,
    const float* __restrict__ BBE, const float* __restrict__ MEANV,
    float* __restrict__ out)
{
    __shared__ __align__(16) char smem[52224];
    int t  = threadIdx.x;
    int lane = t & 63, w = t >> 6;
    int b  = blockIdx.x & 7;
    int it = blockIdx.x >> 3;
    int i0 = it << 5;
    int m = lane & 15, q = lane >> 4;

    // ---- stage: combine partials -> Obuf ----
    float* Lsh0 = (float*)smem;                 // [64] f32 (Abuf region)
    bf16*  Obuf = (bf16*)(smem + 43520);        // [32][136] bf16
    int base2 = (b * 64 + it) * 2;
    if (t < 64) Lsh0[t] = PARTL[base2 * 32 + t];
    __syncthreads();
    {
        const float* P0 = PARTO + (size_t)base2 * 4096;
        #pragma unroll
        for (int pass = 0; pass < 4; ++pass) {
            int idx = pass * 1024 + t * 4;
            int r = idx >> 7, cc2 = idx & 127;
            f32x4 v0 = *(const f32x4*)(P0 + r * 128 + cc2);
            f32x4 v1 = *(const f32x4*)(P0 + 4096 + r * 128 + cc2);
            float inv = 1.0f / (Lsh0[r] + Lsh0[32 + r]);
            bf16x4 o;
            #pragma unroll
            for (int e = 0; e < 4; ++e) o[e] = (bf16)((v0[e] + v1[e]) * inv);
            *(bf16x4*)&Obuf[r * 136 + cc2] = o;
        }
    }
    __syncthreads();

    // ---- Phase B: out rows i0..i0+31 = sum_terms A_term @ G_term + bias ----
    bf16* Abuf = (bf16*)smem;                   // [32][136]
    bf16* Bbuf = (bf16*)(smem + 8704);          // [128][136]

    f32x4 eacc[2][2];
    #pragma unroll
    for (int rb = 0; rb < 2; ++rb)
        #pragma unroll
        for (int cb = 0; cb < 2; ++cb)
            eacc[rb][cb] = {0.f, 0.f, 0.f, 0.f};

    const bf16* Bsrc[4] = {G1T, G2T, G3T, WCT};
    int arow = t >> 3, ao = (t & 7) * 16;
    int brow = t >> 1, bo2 = (t & 1) * 64;
    int c = i0 + arow;

    for (int term = 0; term < 4; ++term) {
        if (term < 3) {
            const bf16* src;
            if (term == 0) src = ops16 + ((size_t)(b * CC + c)) * DD;
            else {
                int ridx = relations[((size_t)b * (CC - 2) + min(c, CC - 3)) * 2 + (term - 1)];
                src = ops16 + ((size_t)(b * CC) + ridx) * DD;
            }
            *(uint4*)&Abuf[arow * 136 + ao]     = *(const uint4*)(src + ao);
            *(uint4*)&Abuf[arow * 136 + ao + 8] = *(const uint4*)(src + ao + 8);
        }
        const uint4* bs = (const uint4*)(Bsrc[term] + brow * 128 + bo2);
        uint4* bd = (uint4*)&Bbuf[brow * 136 + bo2];
        #pragma unroll
        for (int ii = 0; ii < 8; ++ii) bd[ii] = bs[ii];
        __syncthreads();

        const bf16* Asrc = (term == 3) ? Obuf : Abuf;
        #pragma unroll
        for (int kc = 0; kc < 4; ++kc) {
            bf16x8 bfr[2];
            #pragma unroll
            for (int cb = 0; cb < 2; ++cb)
                bfr[cb] = *(const bf16x8*)&Bbuf[(w * 32 + cb * 16 + m) * 136 + kc * 32 + q * 8];
            #pragma unroll
            for (int rb = 0; rb < 2; ++rb) {
                bf16x8 afr = *(const bf16x8*)&Asrc[(rb * 16 + m) * 136 + kc * 32 + q * 8];
                eacc[rb][0] = MFMA16(afr, bfr[0], eacc[rb][0]);
                eacc[rb][1] = MFMA16(afr, bfr[1], eacc[rb][1]);
            }
        }
        __syncthreads();
    }
    #pragma unroll
    for (int cb = 0; cb < 2; ++cb) {
        int col = w * 32 + cb * 16 + m;
        float bias = BBM[col];
        #pragma unroll
        for (int rb = 0; rb < 2; ++rb) {
            #pragma unroll
            for (int r = 0; r < 4; ++r) {
                int cg = i0 + rb * 16 + q * 4 + r;
                if (cg < CC - 2)
                    out[((size_t)(b * CC) + cg) * DD + col] = eacc[rb][cb][r] + bias;
            }
        }
    }

    // ---- edge rows 2046/2047: only the last i-tile of each b ----
    if (i0 == CC - 32) {
        __syncthreads();
        float* mv2 = (float*)smem;             // [2][128]
        int grp = t >> 7, tlx = t & 127;
        mv2[grp * 128 + tlx] = MEANV[((size_t)b * 2 + grp) * 128 + tlx];
        __syncthreads();
        int which = grp;
        const bf16* G    = which ? GEN : GBN;
        const float* Bv  = which ? BBE : BBB;
        const bf16* orow = Obuf + (30 + which) * 136;   // rows 2046/2047
        float a = Bv[tlx];
        const float* mv = mv2 + grp * 128;
        for (int d = 0; d < 128; ++d) {
            a += mv[d] * (float)G[d * 128 + tlx];
            a += (float)orow[d] * (float)WCN[d * 128 + tlx];
        }
        out[((size_t)b * CC + (CC - 2 + which)) * DD + tlx] = a;
    }
}

// =====================================================================
extern "C" void kernel_launch(void* const* d_in, const int* in_sizes, int n_in,
                              void* d_out, int out_size, void* d_ws, size_t ws_size,
                              hipStream_t stream)
{
    const float* ops      = (const float*)d_in[0];
    const int*  relations = (const int*)d_in[1];
    const int*  begins    = (const int*)d_in[2];
    const int*  ends      = (const int*)d_in[3];
    const float* mask     = (const float*)d_in[4];
    const float* Wbegin   = (const float*)d_in[5];
    const float* bbegin   = (const float*)d_in[6];
    const float* Wend     = (const float*)d_in[7];
    const float* bend     = (const float*)d_in[8];
    const float* Wmix3    = (const float*)d_in[9];
    const float* bmix3    = (const float*)d_in[10];
    const float* Wqkv     = (const float*)d_in[11];
    const float* bqkv     = (const float*)d_in[12];
    const float* wscore   = (const float*)d_in[13];
    const float* bscore   = (const float*)d_in[14];
    const float* Wout     = (const float*)d_in[15];
    const float* bout     = (const float*)d_in[16];
    const float* Wmix2    = (const float*)d_in[17];
    const float* bmix2    = (const float*)d_in[18];
    float* outp = (float*)d_out;

    char* ws = (char*)d_ws;
    bf16*  PK    = (bf16*)(ws + WS_PK);
    bf16*  OPS16 = (bf16*)(ws + WS_OPS16);
    float* sqf   = (float*)(ws + WS_SQF);
    float* skf   = (float*)(ws + WS_SKF);
    bf16*  G1T   = (bf16*)(ws + WS_G1T);
    bf16*  G2T   = (bf16*)(ws + WS_G2T);
    bf16*  G3T   = (bf16*)(ws + WS_G3T);
    bf16*  WCT   = (bf16*)(ws + WS_WCT);
    bf16*  GBT   = (bf16*)(ws + WS_GBT);
    bf16*  GET   = (bf16*)(ws + WS_GET);
    bf16*  WCN   = (bf16*)(ws + WS_WCN);
    bf16*  GBN   = (bf16*)(ws + WS_GBN);
    bf16*  GEN   = (bf16*)(ws + WS_GEN);
    bf16*  UQK   = (bf16*)(ws + WS_UQK);
    float* BBM   = (float*)(ws + WS_BBM);
    float* BBB   = (float*)(ws + WS_BBB);
    float* BBE   = (float*)(ws + WS_BBE);
    float* SC    = (float*)(ws + WS_SC);
    unsigned char* MBITS = (unsigned char*)(ws + WS_MB);
    float* MEANV = (float*)(ws + WS_MEANV);
    float* PARTO = (float*)(ws + WS_PARTO);
    float* PARTL = (float*)(ws + WS_PARTL);

    k_prepcast<<<dim3(1137), dim3(256), 0, stream>>>(
        ops, OPS16, begins, ends,
        Wmix3, Wmix2, Wout, Wbegin, Wend, Wqkv, bqkv, wscore, bscore,
        bmix3, bout, bmix2, bbegin, bend,
        G1T, G2T, G3T, WCT, GBT, GET, WCN, GBN, GEN,
        UQK, BBM, BBB, BBE, SC, MEANV);

    k_v<<<dim3(2304), dim3(256), 0, stream>>>(
        OPS16, Wqkv, bqkv, UQK, SC, mask, PK, sqf, skf, MBITS);

    k_att<<<dim3(1024), dim3(512), 0, stream>>>(
        MBITS, PK, sqf, skf, PARTO, PARTL);

    k_epi<<<dim3(512), dim3(256), 0, stream>>>(
        PARTO, PARTL, OPS16, relations,
        G1T, G2T, G3T, WCT, GBN, GEN, WCN, BBM, BBB, BBE, MEANV, outp);
}

// Round 8
// 274.168 us; speedup vs baseline: 1.0495x; 1.0495x over previous
//
#include <hip/hip_runtime.h>
#include <cstddef>

typedef __bf16 bf16;
typedef __bf16 bf16x4 __attribute__((ext_vector_type(4)));
typedef __bf16 bf16x8 __attribute__((ext_vector_type(8)));
typedef float  f32x4  __attribute__((ext_vector_type(4)));

#define MFMA16(a, b, c) __builtin_amdgcn_mfma_f32_16x16x32_bf16((a), (b), (c), 0, 0, 0)

// ---------------- constants ----------------
#define BB 8
#define CC 2048
#define DD 128
#define JJN 128

// ws layout (bytes)
#define WS_PK    ((size_t)0)          // bf16 [8][64jc][8nb][4q][16m][8e]
#define WS_OATT  ((size_t)4194304)    // (unused now)
#define WS_OPS16 ((size_t)8388608)    // bf16 [8][2048][128]
#define WS_SQF   ((size_t)12582912)   // f32  [8][2048]
#define WS_SKF   ((size_t)12648448)   // f32  [8][2048]
#define WS_G1T   ((size_t)12713984)   // bf16 [128][128] (transposed: [e][d])
#define WS_G2T   ((size_t)12746752)
#define WS_G3T   ((size_t)12779520)
#define WS_WCT   ((size_t)12812288)
#define WS_GBT   ((size_t)12845056)
#define WS_GET   ((size_t)12877824)
#define WS_UQK   ((size_t)12910592)   // bf16 [2][128]
#define WS_BBM   ((size_t)12911104)   // f32 [128]
#define WS_BBB   ((size_t)12911616)   // f32 [128]
#define WS_BBE   ((size_t)12912128)   // f32 [128]
#define WS_SC    ((size_t)12912640)   // f32 [2]
#define WS_WCN   ((size_t)12913152)   // bf16 [128][128] non-transposed [d][e]
#define WS_GBN   ((size_t)12945920)
#define WS_GEN   ((size_t)12978688)
#define WS_MB    ((size_t)13011456)   // u8  [8][2048][256] packed mask bits (4 MiB)
#define WS_MEANV ((size_t)17205760)   // f32 [16][128] begin/end gather means

// =====================================================================
// Kernel PREPCAST:
//   wg 0          : vector folds (uqk, BBM/BBB/BBE, sc)
//   wg 1..16      : begin/end gather means (f32, ILP-unrolled)
//   wg 17..2064   : mask bit-pack (134 MB stream -> 4.2 MB bits)
//   wg 2065..2160 : weight-product folds
//   wg 2161..3184 : ops cast f32->bf16
// =====================================================================
__global__ __launch_bounds__(256) void k_prepcast(
    const float* __restrict__ ops, bf16* __restrict__ ops16,
    const float* __restrict__ mask, const int* __restrict__ begins,
    const int* __restrict__ ends,
    const float* __restrict__ Wmix3, const float* __restrict__ Wmix2,
    const float* __restrict__ Wout,  const float* __restrict__ Wbegin,
    const float* __restrict__ Wend,  const float* __restrict__ Wqkv,
    const float* __restrict__ bqkv,  const float* __restrict__ wscore,
    const float* __restrict__ bscore,const float* __restrict__ bmix3,
    const float* __restrict__ bout,  const float* __restrict__ bmix2,
    const float* __restrict__ bbegin,const float* __restrict__ bend,
    bf16* __restrict__ G1T, bf16* __restrict__ G2T, bf16* __restrict__ G3T,
    bf16* __restrict__ WCT, bf16* __restrict__ GBT, bf16* __restrict__ GET,
    bf16* __restrict__ WCN, bf16* __restrict__ GBN, bf16* __restrict__ GEN,
    bf16* __restrict__ uqk, float* __restrict__ BBM, float* __restrict__ BBB,
    float* __restrict__ BBE, float* __restrict__ sc,
    unsigned char* __restrict__ MBITS, float* __restrict__ MEANV)
{
    __shared__ bf16  LshT[128 * 132];
    __shared__ float Rsh[128 * 8];
    int wg = blockIdx.x;
    int t  = threadIdx.x;

    if (wg == 0) {
        // ===== vector folds, fully coalesced via LDS staging =====
        for (int half = 0; half < 2; ++half) {
            #pragma unroll
            for (int pass = 0; pass < 16; ++pass) {       // stage [e][d]
                int idx = pass * 256 + t;
                int d   = idx >> 5;
                int e0  = (idx & 31) * 4;
                f32x4 v = *(const f32x4*)(Wqkv + d*384 + half*128 + e0);
                #pragma unroll
                for (int jj = 0; jj < 4; ++jj)
                    LshT[(e0 + jj)*132 + d] = (bf16)v[jj];
            }
            if (t < 32) {
                f32x4 wv = *(const f32x4*)(wscore + half*128 + t*4);
                #pragma unroll
                for (int jj = 0; jj < 4; ++jj) Rsh[t*4 + jj] = wv[jj];
            }
            __syncthreads();
            if (t < 128) {
                float s = 0.f;
                for (int e = 0; e < 128; ++e)
                    s += (float)LshT[e*132 + t] * Rsh[e];
                uqk[half*128 + t] = (bf16)s;
            }
            __syncthreads();
        }
        // Phase 2: BBM/BBB/BBE components.
        float bm = 0.f, bb_ = 0.f, be_ = 0.f, bon = 0.f;
        for (int half = 0; half < 2; ++half) {
            #pragma unroll
            for (int pass = 0; pass < 16; ++pass) {       // stage [f][e]
                int idx = pass * 256 + t;
                int f   = idx >> 5;
                int e0  = (idx & 31) * 4;
                f32x4 v = *(const f32x4*)(Wmix2 + (size_t)(half*128 + f)*128 + e0);
                #pragma unroll
                for (int jj = 0; jj < 4; ++jj)
                    LshT[f*132 + e0 + jj] = (bf16)v[jj];
            }
            if (t < 32) {
                if (half == 0) {
                    f32x4 v0 = *(const f32x4*)(bmix3  + t*4);
                    f32x4 v1 = *(const f32x4*)(bbegin + t*4);
                    f32x4 v2 = *(const f32x4*)(bend   + t*4);
                    #pragma unroll
                    for (int jj = 0; jj < 4; ++jj) {
                        Rsh[t*4 + jj]       = v0[jj];
                        Rsh[128 + t*4 + jj] = v1[jj];
                        Rsh[256 + t*4 + jj] = v2[jj];
                    }
                } else {
                    f32x4 v3 = *(const f32x4*)(bout + t*4);
                    #pragma unroll
                    for (int jj = 0; jj < 4; ++jj) Rsh[t*4 + jj] = v3[jj];
                }
            }
            __syncthreads();
            if (t < 128) {
                if (half == 0) {
                    for (int f = 0; f < 128; ++f) {
                        float wv = (float)LshT[f*132 + t];
                        bm  += Rsh[f]       * wv;
                        bb_ += Rsh[128 + f] * wv;
                        be_ += Rsh[256 + f] * wv;
                    }
                } else {
                    for (int f = 0; f < 128; ++f)
                        bon += Rsh[f] * (float)LshT[f*132 + t];
                }
            }
            __syncthreads();
        }
        if (t < 128) {
            float bm2 = bmix2[t];
            BBM[t] = bm  + bon + bm2;
            BBB[t] = bb_ + bon + bm2;
            BBE[t] = be_ + bon + bm2;
        }
        // Phase 3: sc
        if (t >= 128) {
            int e2 = t - 128;
            Rsh[512 + e2] = bqkv[e2]       * wscore[e2];
            Rsh[640 + e2] = bqkv[128 + e2] * wscore[128 + e2];
        }
        __syncthreads();
        if (t == 0) {
            float cq = 0.f, ck = 0.f;
            for (int e2 = 0; e2 < 128; ++e2) {
                cq += Rsh[512 + e2];
                ck += Rsh[640 + e2];
            }
            sc[0] = cq + bscore[0];
            sc[1] = ck;
        }
        return;
    }
    if (wg <= 16) {
        // ===== begin/end gather means (f32 ops, ILP via unroll-8) =====
        int task = wg - 1;
        int b2 = task >> 1, which = task & 1;
        const int* idxp = which ? (ends + b2 * JJN) : (begins + b2 * JJN);
        int* ish = (int*)Rsh;
        if (t < JJN) ish[t] = idxp[t];
        __syncthreads();
        int d = t & 127, half = t >> 7;
        const float* opsb = ops + (size_t)b2 * CC * DD;
        float s = 0.f;
        #pragma unroll 8
        for (int j = 0; j < 64; ++j) {
            int r = ish[half * 64 + j];
            s += opsb[(size_t)r * DD + d];
        }
        float* fsh = Rsh + 256;
        fsh[half * 128 + d] = s;
        __syncthreads();
        if (t < 128)
            MEANV[task * 128 + t] = (fsh[t] + fsh[128 + t]) * (1.0f / (float)JJN);
        return;
    }
    if (wg <= 2064) {
        // ===== mask bit-pack: 16384 f32 -> 2048 bytes per block =====
        int p = wg - 17;
        size_t base = (size_t)p * 16384;
        const float* mp = mask + base;
        unsigned char* ob = MBITS + (base >> 3);
        #pragma unroll
        for (int k = 0; k < 8; ++k) {
            size_t fo = (size_t)k * 2048 + (size_t)t * 8;
            f32x4 a = __builtin_nontemporal_load((const f32x4*)(mp + fo));
            f32x4 c = __builtin_nontemporal_load((const f32x4*)(mp + fo + 4));
            unsigned byte = 0;
            #pragma unroll
            for (int e = 0; e < 4; ++e) {
                byte |= (a[e] != 0.f ? 1u : 0u) << e;
                byte |= (c[e] != 0.f ? 1u : 0u) << (4 + e);
            }
            ob[k * 256 + t] = (unsigned char)byte;
        }
        return;
    }
    if (wg <= 2160) {
        // ===== weight-product folds =====
        int id  = wg - 2065;
        int mat = id >> 4, sub = id & 15;
        const float* L; const float* R; bf16* O; bf16* O2;
        switch (mat) {
            case 0: L = Wmix3;           R = Wmix2;           O = G1T; O2 = nullptr; break;
            case 1: L = Wmix3 + 128*128; R = Wmix2;           O = G2T; O2 = nullptr; break;
            case 2: L = Wmix3 + 256*128; R = Wmix2;           O = G3T; O2 = nullptr; break;
            case 3: L = Wout;            R = Wmix2 + 128*128; O = WCT; O2 = WCN; break;
            case 4: L = Wbegin;          R = Wmix2;           O = GBT; O2 = GBN; break;
            default:L = Wend;            R = Wmix2;           O = GET; O2 = GEN; break;
        }
        int e0 = sub * 8;
        #pragma unroll
        for (int pass = 0; pass < 16; ++pass) {
            int idx = pass * 256 + t;
            int d   = idx >> 5;
            int f0  = (idx & 31) * 4;
            f32x4 v = *(const f32x4*)(L + d * 128 + f0);
            #pragma unroll
            for (int jj = 0; jj < 4; ++jj)
                LshT[(f0 + jj) * 132 + d] = (bf16)v[jj];
        }
        #pragma unroll
        for (int pass = 0; pass < 4; ++pass) {
            int idx = pass * 256 + t;
            int f   = idx >> 3;
            int ee  = idx & 7;
            Rsh[f * 8 + ee] = R[f * 128 + e0 + ee];
        }
        __syncthreads();
        int ee = t >> 5;
        int e  = e0 + ee;
        int d0 = (t & 31) * 4;
        float s[4] = {0.f, 0.f, 0.f, 0.f};
        for (int f = 0; f < 128; ++f) {
            bf16x4 lv = *(const bf16x4*)&LshT[f * 132 + d0];
            float rv = Rsh[f * 8 + ee];
            #pragma unroll
            for (int dd = 0; dd < 4; ++dd)
                s[dd] += (float)lv[dd] * rv;
        }
        #pragma unroll
        for (int dd = 0; dd < 4; ++dd) {
            O[e * 128 + d0 + dd] = (bf16)s[dd];
            if (O2) O2[(d0 + dd) * 128 + e] = (bf16)s[dd];
        }
        return;
    }
    // ---- cast ----
    size_t i = (size_t)(wg - 2161) * 256 + t;
    f32x4 a = *(const f32x4*)(ops + i * 8);
    f32x4 b = *(const f32x4*)(ops + i * 8 + 4);
    bf16x8 o;
    #pragma unroll
    for (int e = 0; e < 4; ++e) { o[e] = (bf16)a[e]; o[4 + e] = (bf16)b[e]; }
    *(bf16x8*)(ops16 + i * 8) = o;
}

// =====================================================================
// Kernel V: V = ops@Wv + b_v in PK layout (round-1 version, 128 blocks).
// =====================================================================
__global__ __launch_bounds__(256) void k_v(
    const bf16* __restrict__ ops16, const float* __restrict__ Wqkv,
    const float* __restrict__ bqkv, const bf16* __restrict__ uqk,
    const float* __restrict__ sc,
    bf16* __restrict__ PK, float* __restrict__ sqf, float* __restrict__ skf)
{
    __shared__ bf16 A[144 * 136];     // also reused as 32 KB pack buffer
    int b  = blockIdx.x >> 4;
    int jt = (blockIdx.x & 15) * 128;
    int t  = threadIdx.x;
    #pragma unroll
    for (int pass = 0; pass < 16; ++pass) {
        int idx = pass * 256 + t;
        int d   = idx >> 5;
        int n0  = (idx & 31) * 4;
        f32x4 v = *(const f32x4*)(Wqkv + d*384 + 256 + n0);
        #pragma unroll
        for (int jj = 0; jj < 4; ++jj)
            A[(n0 + jj)*136 + d] = (bf16)v[jj];
    }
    {
        int row = t >> 7, col = t & 127;
        A[(128 + row)*136 + col] = uqk[row*128 + col];
    }
    for (int idx = t; idx < 14*136; idx += 256)
        A[130*136 + idx] = (bf16)0.f;
    __syncthreads();

    int lane = t & 63, w = t >> 6;
    int m = lane & 15, q = lane >> 4;
    f32x4 acc[9][2];
    #pragma unroll
    for (int rb = 0; rb < 9; ++rb)
        #pragma unroll
        for (int cb = 0; cb < 2; ++cb)
            acc[rb][cb] = {0.f, 0.f, 0.f, 0.f};

    const bf16* opsb = ops16 + (size_t)b * CC * DD;
    #pragma unroll
    for (int kc = 0; kc < 4; ++kc) {
        bf16x8 bfr[2];
        #pragma unroll
        for (int cb = 0; cb < 2; ++cb) {
            int j = jt + w*32 + cb*16 + m;
            bfr[cb] = *(const bf16x8*)(opsb + (size_t)j*DD + kc*32 + q*8);
        }
        #pragma unroll
        for (int rb = 0; rb < 9; ++rb) {
            bf16x8 afr = *(const bf16x8*)&A[(rb*16 + m)*136 + kc*32 + q*8];
            acc[rb][0] = MFMA16(afr, bfr[0], acc[rb][0]);
            acc[rb][1] = MFMA16(afr, bfr[1], acc[rb][1]);
        }
    }
    float cqb = sc[0], ckv = sc[1];
    #pragma unroll
    for (int cb = 0; cb < 2; ++cb) {
        int j = jt + w*32 + cb*16 + m;
        if (q == 0) {
            sqf[b*CC + j] = acc[8][cb][0] + cqb;
            skf[b*CC + j] = acc[8][cb][1] + ckv;
        }
    }
    __syncthreads();               // all waves done reading A
    bf16* pack = A;                // 16384 elems = 32 KB
    #pragma unroll
    for (int cb = 0; cb < 2; ++cb) {
        int qq_base = cb*2 + (m>>3);
        int e       = m & 7;
        #pragma unroll
        for (int rb = 0; rb < 8; ++rb) {
            #pragma unroll
            for (int r = 0; r < 4; ++r) {
                float v = acc[rb][cb][r] + bqkv[256 + rb*16 + q*4 + r];
                pack[w*4096 + rb*512 + qq_base*128 + (q*4+r)*8 + e] = (bf16)v;
            }
        }
    }
    __syncthreads();
    bf16* pkb = PK + (size_t)b * DD * CC + (size_t)jt * 128;
    #pragma unroll
    for (int pass = 0; pass < 8; ++pass) {
        int lidx = pass * 256 + t;
        *(uint4*)(pkb + (size_t)lidx * 8) = *(const uint4*)&pack[lidx * 8];
    }
}

// =====================================================================
// Kernel ATT+EPI (fused): bit-mask softmax-GEMM, O kept in LDS,
// followed by the 4-term output GEMM and (tile 63) the edge rows.
// =====================================================================
__device__ __forceinline__ void load_vb(const bf16* __restrict__ pkb, int jc,
                                        int q, int m, bf16x8 vb[8])
{
    #pragma unroll
    for (int nb = 0; nb < 8; ++nb)
        vb[nb] = *(const bf16x8*)(pkb + ((size_t)(((jc*8 + nb)*4 + q)*16 + m)) * 8);
}

__device__ __forceinline__ void substep(const float* __restrict__ skb,
    unsigned mbyte, int st, int sub, int q, float sq,
    const bf16x8 vb[8], float& lsum, f32x4 acc[8])
{
    int jo = st * 64 + sub * 32 + q * 8;
    f32x4 s0 = *(const f32x4*)(skb + jo);
    f32x4 s1 = *(const f32x4*)(skb + jo + 4);
    float sks[8] = {s0[0], s0[1], s0[2], s0[3], s1[0], s1[1], s1[2], s1[3]};
    bf16x8 a;
    #pragma unroll
    for (int e = 0; e < 8; ++e) {
        float tv = sq + sks[e];
        float lr = fmaxf(tv, 0.01f * tv);
        float pm = (float)((mbyte >> e) & 1u);
        float p  = __expf(lr * pm);
        lsum += p;
        a[e] = (bf16)p;
    }
    #pragma unroll
    for (int nb = 0; nb < 8; ++nb)
        acc[nb] = MFMA16(a, vb[nb], acc[nb]);
}

__global__ __launch_bounds__(256) void k_attepi(
    const unsigned char* __restrict__ MBITS, const bf16* __restrict__ PK,
    const float* __restrict__ sqf, const float* __restrict__ skf,
    const bf16* __restrict__ ops16, const int* __restrict__ relations,
    const bf16* __restrict__ G1T, const bf16* __restrict__ G2T,
    const bf16* __restrict__ G3T, const bf16* __restrict__ WCT,
    const bf16* __restrict__ GBN, const bf16* __restrict__ GEN,
    const bf16* __restrict__ WCN,
    const float* __restrict__ BBM, const float* __restrict__ BBB,
    const float* __restrict__ BBE, const float* __restrict__ MEANV,
    float* __restrict__ out)
{
    __shared__ __align__(16) char smem[52224];
    int t    = threadIdx.x;
    int lane = t & 63, w = t >> 6;
    int b    = blockIdx.x & 7;
    int i0   = (blockIdx.x >> 3) << 5;
    int m = lane & 15, q = lane >> 4;

    unsigned char* Lb  = (unsigned char*)smem;              // [32][272] = 8704 B
    float*         skb = (float*)(smem + 8704 + w * 2048);  // 4 x 512 f32

    // ---- one-shot stage: packed mask bits (8 KB) + sk row ----
    {
        int row = t >> 3, seg = t & 7;
        const uint4* src = (const uint4*)(MBITS
            + ((size_t)(b * CC + i0 + row)) * 256 + seg * 32);
        uint4 v0 = src[0], v1 = src[1];
        *(uint4*)(Lb + row * 272 + seg * 32)      = v0;
        *(uint4*)(Lb + row * 272 + seg * 32 + 16) = v1;
    }
    {
        const float* src = skf + b * CC + w * 512;
        f32x4 v0 = *(const f32x4*)(src + lane * 4);
        f32x4 v1 = *(const f32x4*)(src + 256 + lane * 4);
        *(f32x4*)(skb + lane * 4)       = v0;
        *(f32x4*)(skb + 256 + lane * 4) = v1;
    }
    float sq0 = sqf[b * CC + i0 + m];
    float sq1 = sqf[b * CC + i0 + 16 + m];
    const bf16* pkb = PK + (size_t)b * DD * CC;
    int jc0 = w * 16;

    f32x4 acc0[8], acc1[8];
    #pragma unroll
    for (int nb = 0; nb < 8; ++nb) {
        acc0[nb] = {0.f, 0.f, 0.f, 0.f};
        acc1[nb] = {0.f, 0.f, 0.f, 0.f};
    }
    float lsum0 = 0.f, lsum1 = 0.f;
    __syncthreads();

    for (int st = 0; st < 8; ++st) {
        #pragma unroll
        for (int sub = 0; sub < 2; ++sub) {
            bf16x8 vb[8];
            load_vb(pkb, jc0 + st * 2 + sub, q, m, vb);
            int bo = w * 64 + st * 8 + sub * 4 + q;
            unsigned mb0 = Lb[m * 272 + bo];
            unsigned mb1 = Lb[(16 + m) * 272 + bo];
            substep(skb, mb0, st, sub, q, sq0, vb, lsum0, acc0);
            substep(skb, mb1, st, sub, q, sq1, vb, lsum1, acc1);
        }
    }

    // ---- softmax-normalize epilogue -> Obuf (LDS, bf16 [32][136]) ----
    __syncthreads();
    float* Osh  = (float*)(smem + 8704);        // [64][132] f32 = 33792 B
    float* Lsh  = (float*)(smem + 42496);       // [64] f32
    bf16*  Obuf = (bf16*)(smem + 43520);        // [32][136] bf16 = 8704 B
    #pragma unroll
    for (int tile = 0; tile < 2; ++tile) {
        float ls = tile ? lsum1 : lsum0;
        ls += __shfl_xor(ls, 16, 64);
        ls += __shfl_xor(ls, 32, 64);
        if (q == 0) Lsh[w * 16 + m] = ls;
        const f32x4* acc = tile ? acc1 : acc0;
        #pragma unroll
        for (int nb = 0; nb < 8; ++nb)
            #pragma unroll
            for (int r = 0; r < 4; ++r)
                Osh[(w * 16 + q * 4 + r) * 132 + nb * 16 + m] = acc[nb][r];
        __syncthreads();

        int r   = t >> 4;
        int c0e = (t & 15) * 8;
        float l = Lsh[r] + Lsh[16 + r] + Lsh[32 + r] + Lsh[48 + r];
        float inv = 1.0f / l;
        bf16x8 o;
        #pragma unroll
        for (int e = 0; e < 8; ++e) {
            float s = Osh[r * 132 + c0e + e] + Osh[(16 + r) * 132 + c0e + e]
                    + Osh[(32 + r) * 132 + c0e + e] + Osh[(48 + r) * 132 + c0e + e];
            o[e] = (bf16)(s * inv);
        }
        *(bf16x8*)&Obuf[(tile * 16 + r) * 136 + c0e] = o;
        __syncthreads();
    }

    // ---- Phase B: out rows i0..i0+31 = sum_terms A_term @ G_term + bias ----
    bf16* Abuf = (bf16*)smem;                   // [32][136] (= Lb region, dead)
    bf16* Bbuf = (bf16*)(smem + 8704);          // [128][136]

    f32x4 eacc[2][2];
    #pragma unroll
    for (int rb = 0; rb < 2; ++rb)
        #pragma unroll
        for (int cb = 0; cb < 2; ++cb)
            eacc[rb][cb] = {0.f, 0.f, 0.f, 0.f};

    const bf16* Bsrc[4] = {G1T, G2T, G3T, WCT};
    int arow = t >> 3, ao = (t & 7) * 16;
    int brow = t >> 1, bo2 = (t & 1) * 64;
    int c = i0 + arow;

    for (int term = 0; term < 4; ++term) {
        if (term < 3) {
            const bf16* src;
            if (term == 0) src = ops16 + ((size_t)(b * CC + c)) * DD;
            else {
                int ridx = relations[((size_t)b * (CC - 2) + min(c, CC - 3)) * 2 + (term - 1)];
                src = ops16 + ((size_t)(b * CC) + ridx) * DD;
            }
            *(uint4*)&Abuf[arow * 136 + ao]     = *(const uint4*)(src + ao);
            *(uint4*)&Abuf[arow * 136 + ao + 8] = *(const uint4*)(src + ao + 8);
        }
        const uint4* bs = (const uint4*)(Bsrc[term] + brow * 128 + bo2);
        uint4* bd = (uint4*)&Bbuf[brow * 136 + bo2];
        #pragma unroll
        for (int ii = 0; ii < 8; ++ii) bd[ii] = bs[ii];
        __syncthreads();

        const bf16* Asrc = (term == 3) ? Obuf : Abuf;
        #pragma unroll
        for (int kc = 0; kc < 4; ++kc) {
            bf16x8 bfr[2];
            #pragma unroll
            for (int cb = 0; cb < 2; ++cb)
                bfr[cb] = *(const bf16x8*)&Bbuf[(w * 32 + cb * 16 + m) * 136 + kc * 32 + q * 8];
            #pragma unroll
            for (int rb = 0; rb < 2; ++rb) {
                bf16x8 afr = *(const bf16x8*)&Asrc[(rb * 16 + m) * 136 + kc * 32 + q * 8];
                eacc[rb][0] = MFMA16(afr, bfr[0], eacc[rb][0]);
                eacc[rb][1] = MFMA16(afr, bfr[1], eacc[rb][1]);
            }
        }
        __syncthreads();
    }
    #pragma unroll
    for (int cb = 0; cb < 2; ++cb) {
        int col = w * 32 + cb * 16 + m;
        float bias = BBM[col];
        #pragma unroll
        for (int rb = 0; rb < 2; ++rb) {
            #pragma unroll
            for (int r = 0; r < 4; ++r) {
                int cg = i0 + rb * 16 + q * 4 + r;
                if (cg < CC - 2)
                    out[((size_t)(b * CC) + cg) * DD + col] = eacc[rb][cb][r] + bias;
            }
        }
    }

    // ---- edge rows 2046/2047: only the last i-tile of each b ----
    if (i0 == CC - 32) {
        __syncthreads();                       // Abuf region reuse below
        float* mv2 = (float*)smem;             // [2][128]
        int grp = t >> 7, tl = t & 127;
        mv2[grp * 128 + tl] = MEANV[((size_t)b * 2 + grp) * 128 + tl];
        __syncthreads();
        int which = grp;
        const bf16* G    = which ? GEN : GBN;
        const float* Bv  = which ? BBE : BBB;
        const bf16* orow = Obuf + (30 + which) * 136;   // rows 2046/2047
        float a = Bv[tl];
        const float* mv = mv2 + grp * 128;
        for (int d = 0; d < 128; ++d) {
            a += mv[d] * (float)G[d * 128 + tl];
            a += (float)orow[d] * (float)WCN[d * 128 + tl];
        }
        out[((size_t)b * CC + (CC - 2 + which)) * DD + tl] = a;
    }
}

// =====================================================================
extern "C" void kernel_launch(void* const* d_in, const int* in_sizes, int n_in,
                              void* d_out, int out_size, void* d_ws, size_t ws_size,
                              hipStream_t stream)
{
    const float* ops      = (const float*)d_in[0];
    const int*  relations = (const int*)d_in[1];
    const int*  begins    = (const int*)d_in[2];
    const int*  ends      = (const int*)d_in[3];
    const float* mask     = (const float*)d_in[4];
    const float* Wbegin   = (const float*)d_in[5];
    const float* bbegin   = (const float*)d_in[6];
    const float* Wend     = (const float*)d_in[7];
    const float* bend     = (const float*)d_in[8];
    const float* Wmix3    = (const float*)d_in[9];
    const float* bmix3    = (const float*)d_in[10];
    const float* Wqkv     = (const float*)d_in[11];
    const float* bqkv     = (const float*)d_in[12];
    const float* wscore   = (const float*)d_in[13];
    const float* bscore   = (const float*)d_in[14];
    const float* Wout     = (const float*)d_in[15];
    const float* bout     = (const float*)d_in[16];
    const float* Wmix2    = (const float*)d_in[17];
    const float* bmix2    = (const float*)d_in[18];
    float* outp = (float*)d_out;

    char* ws = (char*)d_ws;
    bf16*  PK    = (bf16*)(ws + WS_PK);
    bf16*  OPS16 = (bf16*)(ws + WS_OPS16);
    float* sqf   = (float*)(ws + WS_SQF);
    float* skf   = (float*)(ws + WS_SKF);
    bf16*  G1T   = (bf16*)(ws + WS_G1T);
    bf16*  G2T   = (bf16*)(ws + WS_G2T);
    bf16*  G3T   = (bf16*)(ws + WS_G3T);
    bf16*  WCT   = (bf16*)(ws + WS_WCT);
    bf16*  GBT   = (bf16*)(ws + WS_GBT);
    bf16*  GET   = (bf16*)(ws + WS_GET);
    bf16*  WCN   = (bf16*)(ws + WS_WCN);
    bf16*  GBN   = (bf16*)(ws + WS_GBN);
    bf16*  GEN   = (bf16*)(ws + WS_GEN);
    bf16*  UQK   = (bf16*)(ws + WS_UQK);
    float* BBM   = (float*)(ws + WS_BBM);
    float* BBB   = (float*)(ws + WS_BBB);
    float* BBE   = (float*)(ws + WS_BBE);
    float* SC    = (float*)(ws + WS_SC);
    unsigned char* MBITS = (unsigned char*)(ws + WS_MB);
    float* MEANV = (float*)(ws + WS_MEANV);

    k_prepcast<<<dim3(3185), dim3(256), 0, stream>>>(
        ops, OPS16, mask, begins, ends,
        Wmix3, Wmix2, Wout, Wbegin, Wend, Wqkv, bqkv, wscore, bscore,
        bmix3, bout, bmix2, bbegin, bend,
        G1T, G2T, G3T, WCT, GBT, GET, WCN, GBN, GEN,
        UQK, BBM, BBB, BBE, SC, MBITS, MEANV);

    k_v<<<dim3(128), dim3(256), 0, stream>>>(
        OPS16, Wqkv, bqkv, UQK, SC, PK, sqf, skf);

    k_attepi<<<dim3(512), dim3(256), 0, stream>>>(
        MBITS, PK, sqf, skf, OPS16, relations,
        G1T, G2T, G3T, WCT, GBN, GEN, WCN, BBM, BBB, BBE, MEANV, outp);
}